// Round 10
// baseline (107.292 us; speedup 1.0000x reference)
//
#include <hip/hip_runtime.h>
#include <hip/hip_bf16.h>
#include <stdint.h>

#define N_B 4
#define NV 4096
#define NE 2048
#define NC 64

typedef float    f32x4  __attribute__((ext_vector_type(4)));
typedef __bf16   bf16x8 __attribute__((ext_vector_type(8)));
typedef unsigned short u16;
typedef u16      u16x8  __attribute__((ext_vector_type(8)));
typedef uint32_t u32x4  __attribute__((ext_vector_type(4)));

__device__ __forceinline__ u16 f2bf_rne(float f) {
    uint32_t u = __builtin_bit_cast(uint32_t, f);
    u += 0x7FFFu + ((u >> 16) & 1u);
    return (u16)(u >> 16);
}
__device__ __forceinline__ float bf2f(u16 h) {
    uint32_t u = ((uint32_t)h) << 16;
    return __builtin_bit_cast(float, u);
}
__device__ __forceinline__ f32x4 mfma_bf16(u16x8 a, u16x8 b, f32x4 c) {
    return __builtin_amdgcn_mfma_f32_16x16x32_bf16(
        __builtin_bit_cast(bf16x8, a), __builtin_bit_cast(bf16x8, b), c, 0, 0, 0);
}
// 8 bits -> 8 bf16 (1.0/0.0). u16 lane j = bit j.
__device__ __forceinline__ u16x8 expand8(uint32_t byte) {
    u32x4 w;
#pragma unroll
    for (int p = 0; p < 4; ++p) {
        const uint32_t lo = (byte >> (2 * p)) & 1u;
        const uint32_t hi = (byte >> (2 * p + 1)) & 1u;
        w[p] = (lo | (hi << 16)) * 0x3F80u;
    }
    return __builtin_bit_cast(u16x8, w);
}

// ---------------------------------------------------------------------------
// Kernel P: pack H (fp32 0/1) into bitmasks, both orientations, + degree
// partials via popcount.
// ---------------------------------------------------------------------------
__global__ __launch_bounds__(256) void k_pack(const float* __restrict__ H,
                                              uint32_t* __restrict__ HB,
                                              uint32_t* __restrict__ HT,
                                              float* __restrict__ dvP,
                                              float* __restrict__ deP) {
    __shared__ float tile[64][65];
    const int n  = blockIdx.z;
    const int v0 = blockIdx.y * 64;
    const int e0 = blockIdx.x * 64;
    const int t = threadIdx.x, w = t >> 6, l = t & 63;

    const float* __restrict__ Hn = H + ((size_t)n * NV + v0) * NE + e0;

#pragma unroll 4
    for (int i = 0; i < 16; ++i) {
        const int row = w * 16 + i;
        const float h = Hn[(size_t)row * NE + l];
        tile[row][l] = h;
        const unsigned long long m = __ballot(h != 0.0f);
        if (l == 0)
            dvP[((size_t)blockIdx.x * N_B + n) * NV + v0 + row] = (float)__popcll(m);
        if (l < 2)
            HB[(((size_t)n * (NV / 16) + ((v0 + row) >> 4)) * (NE / 32) + (e0 >> 5) + l) * 16 +
               ((v0 + row) & 15)] = (uint32_t)(m >> (32 * l));
    }
    __syncthreads();

#pragma unroll 4
    for (int i = 0; i < 16; ++i) {
        const int col = w * 16 + i;
        const float h = tile[l][col];
        const unsigned long long m = __ballot(h != 0.0f);
        if (l == 0)
            deP[((size_t)blockIdx.y * N_B + n) * NE + e0 + col] = (float)__popcll(m);
        if (l < 2)
            HT[(((size_t)n * (NE / 16) + ((e0 + col) >> 4)) * (NV / 32) + (v0 >> 5) + l) * 16 +
               ((e0 + col) & 15)] = (uint32_t)(m >> (32 * l));
    }
}

// ---------------------------------------------------------------------------
// Kernel D: collapse degree partials.
// ---------------------------------------------------------------------------
__global__ __launch_bounds__(256) void k_deg(const float* __restrict__ dvP,
                                             const float* __restrict__ deP,
                                             float* __restrict__ dv,
                                             float* __restrict__ de) {
    const int id = blockIdx.x * 256 + threadIdx.x;
    if (id < N_B * NE) {
        float s = 0.f;
        for (int vt = 0; vt < 64; ++vt) s += deP[(size_t)vt * (N_B * NE) + id];
        de[id] = s;
    } else {
        const int j = id - N_B * NE;
        float s = 0.f;
        for (int et = 0; et < 32; ++et) s += dvP[(size_t)et * (N_B * NV) + j];
        dv[j] = s;
    }
}

// ---------------------------------------------------------------------------
// Kernel 1: Yht_{h,l}[n][c][v] (bf16 hi/lo) = transpose of x@theta.
// ---------------------------------------------------------------------------
__global__ __launch_bounds__(256) void k_xtheta(const float* __restrict__ x,
                                                const float* __restrict__ th,
                                                u16* __restrict__ Yh,
                                                u16* __restrict__ Yl) {
    __shared__ float xs[64][65];   // [v][k]
    __shared__ float ts[64][65];   // [k][c]
    const int t = threadIdx.x;
    const int n  = blockIdx.x >> 6;
    const int v0 = (blockIdx.x & 63) * 64;

#pragma unroll
    for (int i = 0; i < 4; ++i) {
        const int idx = i * 256 + t;
        const int row = idx >> 4, q = (idx & 15) * 4;
        const float4 xv = *(const float4*)&x[((size_t)(n * NV + v0 + row)) * 64 + q];
        const float4 tv = *(const float4*)&th[(size_t)row * 64 + q];
        xs[row][q] = xv.x; xs[row][q + 1] = xv.y; xs[row][q + 2] = xv.z; xs[row][q + 3] = xv.w;
        ts[row][q] = tv.x; ts[row][q + 1] = tv.y; ts[row][q + 2] = tv.z; ts[row][q + 3] = tv.w;
    }
    __syncthreads();

    const int v4 = (t & 15) * 4;
    const int c4 = (t >> 4) * 4;
    float acc[4][4] = {};   // [c][v]
#pragma unroll
    for (int k = 0; k < 64; ++k) {
        float tv[4], xv[4];
#pragma unroll
        for (int i = 0; i < 4; ++i) { tv[i] = ts[k][c4 + i]; xv[i] = xs[v4 + i][k]; }
#pragma unroll
        for (int i = 0; i < 4; ++i)
#pragma unroll
            for (int j = 0; j < 4; ++j) acc[i][j] += tv[i] * xv[j];
    }
#pragma unroll
    for (int i = 0; i < 4; ++i) {
        ushort4 hi, lo;
        u16 h;
        h = f2bf_rne(acc[i][0]); hi.x = h; lo.x = f2bf_rne(acc[i][0] - bf2f(h));
        h = f2bf_rne(acc[i][1]); hi.y = h; lo.y = f2bf_rne(acc[i][1] - bf2f(h));
        h = f2bf_rne(acc[i][2]); hi.z = h; lo.z = f2bf_rne(acc[i][2] - bf2f(h));
        h = f2bf_rne(acc[i][3]); hi.w = h; lo.w = f2bf_rne(acc[i][3] - bf2f(h));
        const size_t o = ((size_t)n * 64 + c4 + i) * NV + v0 + v4;
        *(ushort4*)&Yh[o] = hi;
        *(ushort4*)&Yl[o] = lo;
    }
}

// ---------------------------------------------------------------------------
// Kernel 2: vertex->edge MFMA partials. No LDS, no barriers.
// A (cold HBM bit-words) AND B (L2 Y^T fragments): prefetch DEPTH 4,
// unified static modulo-4 rotation (all indices compile-time).
// ---------------------------------------------------------------------------
__global__ __launch_bounds__(256, 4) void k_v2e(const uint32_t* __restrict__ HT,
                                                const u16* __restrict__ Yh,
                                                const u16* __restrict__ Yl,
                                                float* __restrict__ P2) {
    const int n  = blockIdx.z;
    const int sp = blockIdx.y;
    const int e0 = blockIdx.x * 64;
    const int krange = NV / gridDim.y;
    const int kk0 = sp * krange;
    const int S   = krange / 32;   // 16 at s2=8

    const int t = threadIdx.x, w = t >> 6, l = t & 63;
    const int lq = l >> 4, lr = l & 15;
    const int sh = lq * 8;
    const int hstride = (NV / 32) * 16;

    const uint32_t* __restrict__ ht =
        HT + ((size_t)n * (NE / 16) + (e0 >> 4)) * hstride + (kk0 >> 5) * 16 + lr;
    const u16* __restrict__ ybh = Yh + ((size_t)n * 64 + w * 16 + lr) * NV + kk0 + lq * 8;
    const u16* __restrict__ ybl = Yl + ((size_t)n * 64 + w * 16 + lr) * NV + kk0 + lq * 8;

    f32x4 acc0 = {0.f,0.f,0.f,0.f}, acc1 = acc0, acc2 = acc0, acc3 = acc0;

    // pipelines: slot d holds operands of step sb+d
    uint32_t A[4][4];
    u16x8 BH[4], BL[4];
#pragma unroll
    for (int d = 0; d < 4; ++d) {
        A[d][0] = ht[0 * hstride + d * 16];
        A[d][1] = ht[1 * hstride + d * 16];
        A[d][2] = ht[2 * hstride + d * 16];
        A[d][3] = ht[3 * hstride + d * 16];
        BH[d] = *(const u16x8*)(ybh + d * 32);
        BL[d] = *(const u16x8*)(ybl + d * 32);
    }

#define V2E_STEP(s, u, GUARD)                                                 \
    {                                                                         \
        const uint32_t a0 = A[u][0], a1 = A[u][1], a2 = A[u][2], a3 = A[u][3];\
        const u16x8 bh = BH[u], bl = BL[u];                                   \
        if (GUARD) {   /* reload slot u for step s+4: issue EARLY */          \
            A[u][0] = ht[0 * hstride + ((s) + 4) * 16];                       \
            A[u][1] = ht[1 * hstride + ((s) + 4) * 16];                       \
            A[u][2] = ht[2 * hstride + ((s) + 4) * 16];                       \
            A[u][3] = ht[3 * hstride + ((s) + 4) * 16];                       \
            BH[u] = *(const u16x8*)(ybh + ((s) + 4) * 32);                    \
            BL[u] = *(const u16x8*)(ybl + ((s) + 4) * 32);                    \
        }                                                                     \
        u16x8 a;                                                              \
        a = expand8((a0 >> sh) & 0xFF);                                       \
        acc0 = mfma_bf16(a, bh, acc0); acc0 = mfma_bf16(a, bl, acc0);         \
        a = expand8((a1 >> sh) & 0xFF);                                       \
        acc1 = mfma_bf16(a, bh, acc1); acc1 = mfma_bf16(a, bl, acc1);         \
        a = expand8((a2 >> sh) & 0xFF);                                       \
        acc2 = mfma_bf16(a, bh, acc2); acc2 = mfma_bf16(a, bl, acc2);         \
        a = expand8((a3 >> sh) & 0xFF);                                       \
        acc3 = mfma_bf16(a, bh, acc3); acc3 = mfma_bf16(a, bl, acc3);         \
    }

    int sb = 0;
    for (; sb < S - 4; sb += 4) {        // steady state
        V2E_STEP(sb + 0, 0, true)
        V2E_STEP(sb + 1, 1, true)
        V2E_STEP(sb + 2, 2, true)
        V2E_STEP(sb + 3, 3, true)
    }
    // tail block sb = S-4
    V2E_STEP(sb + 0, 0, false)
    V2E_STEP(sb + 1, 1, false)
    V2E_STEP(sb + 2, 2, false)
    V2E_STEP(sb + 3, 3, false)
#undef V2E_STEP

    // D: row e = e0 + eb*16 + lq*4 + reg, col c = w*16 + lr
    float* pb = P2 + (((size_t)sp * N_B + n) * 64 + w * 16 + lr) * NE + e0 + lq * 4;
    *(f32x4*)(pb + 0)  = acc0;
    *(f32x4*)(pb + 16) = acc1;
    *(f32x4*)(pb + 32) = acc2;
    *(f32x4*)(pb + 48) = acc3;
}

// ---------------------------------------------------------------------------
// Kernel 3: Z_{h,l}[n][c][e] = bf16 hi/lo of (sum_sp P2)/de
// ---------------------------------------------------------------------------
__global__ __launch_bounds__(256) void k_red2(const float* __restrict__ P2,
                                              const float* __restrict__ de,
                                              u16* __restrict__ Zh,
                                              u16* __restrict__ Zl, int nsp) {
    const int i = blockIdx.x * 256 + threadIdx.x;   // 0..131071
    const int row = i >> 9;                          // n*64 + c
    const int e4  = (i & 511) * 4;
    const int n   = row >> 6;

    float4 a = make_float4(0.f, 0.f, 0.f, 0.f);
    for (int sp = 0; sp < nsp; ++sp) {
        const float4 p = *(const float4*)&P2[((size_t)sp * 256 + row) * NE + e4];
        a.x += p.x; a.y += p.y; a.z += p.z; a.w += p.w;
    }
    const float4 d = *(const float4*)&de[(size_t)n * NE + e4];
    float z[4] = {a.x / d.x, a.y / d.y, a.z / d.z, a.w / d.w};
    ushort4 hi, lo;
    u16 h;
    h = f2bf_rne(z[0]); hi.x = h; lo.x = f2bf_rne(z[0] - bf2f(h));
    h = f2bf_rne(z[1]); hi.y = h; lo.y = f2bf_rne(z[1] - bf2f(h));
    h = f2bf_rne(z[2]); hi.z = h; lo.z = f2bf_rne(z[2] - bf2f(h));
    h = f2bf_rne(z[3]); hi.w = h; lo.w = f2bf_rne(z[3] - bf2f(h));
    *(ushort4*)&Zh[(size_t)row * NE + e4] = hi;
    *(ushort4*)&Zl[(size_t)row * NE + e4] = lo;
}

// ---------------------------------------------------------------------------
// Kernel 4: edge->vertex MFMA partials. A+B depth-4, no LDS, no barriers.
// ---------------------------------------------------------------------------
__global__ __launch_bounds__(256, 4) void k_e2v(const uint32_t* __restrict__ HB,
                                                const u16* __restrict__ Zh,
                                                const u16* __restrict__ Zl,
                                                float* __restrict__ P3) {
    const int n  = blockIdx.z;
    const int sp = blockIdx.y;
    const int v0 = blockIdx.x * 64;
    const int krange = NE / gridDim.y;
    const int kk0 = sp * krange;
    const int S   = krange / 32;   // 16 at s3=4

    const int t = threadIdx.x, w = t >> 6, l = t & 63;
    const int lq = l >> 4, lr = l & 15;
    const int sh = lq * 8;
    const int estride = (NE / 32) * 16;

    const uint32_t* __restrict__ hb =
        HB + ((size_t)n * (NV / 16) + (v0 >> 4)) * estride + (kk0 >> 5) * 16 + lr;
    const u16* __restrict__ zbh = Zh + ((size_t)n * 64 + w * 16 + lr) * NE + kk0 + lq * 8;
    const u16* __restrict__ zbl = Zl + ((size_t)n * 64 + w * 16 + lr) * NE + kk0 + lq * 8;

    f32x4 acc0 = {0.f,0.f,0.f,0.f}, acc1 = acc0, acc2 = acc0, acc3 = acc0;

    uint32_t A[4][4];
    u16x8 BH[4], BL[4];
#pragma unroll
    for (int d = 0; d < 4; ++d) {
        A[d][0] = hb[0 * estride + d * 16];
        A[d][1] = hb[1 * estride + d * 16];
        A[d][2] = hb[2 * estride + d * 16];
        A[d][3] = hb[3 * estride + d * 16];
        BH[d] = *(const u16x8*)(zbh + d * 32);
        BL[d] = *(const u16x8*)(zbl + d * 32);
    }

#define E2V_STEP(s, u, GUARD)                                                 \
    {                                                                         \
        const uint32_t a0 = A[u][0], a1 = A[u][1], a2 = A[u][2], a3 = A[u][3];\
        const u16x8 bh = BH[u], bl = BL[u];                                   \
        if (GUARD) {                                                          \
            A[u][0] = hb[0 * estride + ((s) + 4) * 16];                       \
            A[u][1] = hb[1 * estride + ((s) + 4) * 16];                       \
            A[u][2] = hb[2 * estride + ((s) + 4) * 16];                       \
            A[u][3] = hb[3 * estride + ((s) + 4) * 16];                       \
            BH[u] = *(const u16x8*)(zbh + ((s) + 4) * 32);                    \
            BL[u] = *(const u16x8*)(zbl + ((s) + 4) * 32);                    \
        }                                                                     \
        u16x8 a;                                                              \
        a = expand8((a0 >> sh) & 0xFF);                                       \
        acc0 = mfma_bf16(a, bh, acc0); acc0 = mfma_bf16(a, bl, acc0);         \
        a = expand8((a1 >> sh) & 0xFF);                                       \
        acc1 = mfma_bf16(a, bh, acc1); acc1 = mfma_bf16(a, bl, acc1);         \
        a = expand8((a2 >> sh) & 0xFF);                                       \
        acc2 = mfma_bf16(a, bh, acc2); acc2 = mfma_bf16(a, bl, acc2);         \
        a = expand8((a3 >> sh) & 0xFF);                                       \
        acc3 = mfma_bf16(a, bh, acc3); acc3 = mfma_bf16(a, bl, acc3);         \
    }

    int sb = 0;
    for (; sb < S - 4; sb += 4) {
        E2V_STEP(sb + 0, 0, true)
        E2V_STEP(sb + 1, 1, true)
        E2V_STEP(sb + 2, 2, true)
        E2V_STEP(sb + 3, 3, true)
    }
    E2V_STEP(sb + 0, 0, false)
    E2V_STEP(sb + 1, 1, false)
    E2V_STEP(sb + 2, 2, false)
    E2V_STEP(sb + 3, 3, false)
#undef E2V_STEP

    float* pb = P3 + (((size_t)sp * N_B + n) * 64 + w * 16 + lr) * NV + v0 + lq * 4;
    *(f32x4*)(pb + 0)  = acc0;
    *(f32x4*)(pb + 16) = acc1;
    *(f32x4*)(pb + 32) = acc2;
    *(f32x4*)(pb + 48) = acc3;
}

// ---------------------------------------------------------------------------
// Kernel 5: out[n][v][c] = (sum_sp P3[sp][n][c][v]) / dv + bias  (transpose)
// ---------------------------------------------------------------------------
__global__ __launch_bounds__(512) void k_red3(const float* __restrict__ P3,
                                              const float* __restrict__ dv,
                                              const float* __restrict__ bias,
                                              float* __restrict__ out, int nsp) {
    __shared__ float lt[64][68];
    const int n  = blockIdx.y;
    const int v0 = blockIdx.x * 64;
    const int t  = threadIdx.x;

    {
        const int c   = t >> 3;
        const int vch = (t & 7) * 8;
        float4 s0 = make_float4(0.f, 0.f, 0.f, 0.f), s1 = s0;
        for (int sp = 0; sp < nsp; ++sp) {
            const size_t base = (((size_t)sp * N_B + n) * 64 + c) * NV + v0 + vch;
            const float4 p0 = *(const float4*)&P3[base];
            const float4 p1 = *(const float4*)&P3[base + 4];
            s0.x += p0.x; s0.y += p0.y; s0.z += p0.z; s0.w += p0.w;
            s1.x += p1.x; s1.y += p1.y; s1.z += p1.z; s1.w += p1.w;
        }
        *(float4*)&lt[c][vch]     = s0;
        *(float4*)&lt[c][vch + 4] = s1;
    }
    const int vw  = t >> 3;
    const int cch = (t & 7) * 8;
    const float dsum = dv[(size_t)n * NV + v0 + vw];
    __syncthreads();

    const float rdv = 1.0f / dsum;
    const float4 b0 = *(const float4*)&bias[cch];
    const float4 b1 = *(const float4*)&bias[cch + 4];
    float4 o0, o1;
    o0.x = lt[cch + 0][vw] * rdv + b0.x;
    o0.y = lt[cch + 1][vw] * rdv + b0.y;
    o0.z = lt[cch + 2][vw] * rdv + b0.z;
    o0.w = lt[cch + 3][vw] * rdv + b0.w;
    o1.x = lt[cch + 4][vw] * rdv + b1.x;
    o1.y = lt[cch + 5][vw] * rdv + b1.y;
    o1.z = lt[cch + 6][vw] * rdv + b1.z;
    o1.w = lt[cch + 7][vw] * rdv + b1.w;
    float* dst = out + ((size_t)n * NV + v0 + vw) * 64 + cch;
    *(float4*)dst       = o0;
    *(float4*)(dst + 4) = o1;
}

// ---------------------------------------------------------------------------
extern "C" void kernel_launch(void* const* d_in, const int* in_sizes, int n_in,
                              void* d_out, int out_size, void* d_ws, size_t ws_size,
                              hipStream_t stream) {
    const float* x     = (const float*)d_in[0];
    const float* H     = (const float*)d_in[1];
    const float* theta = (const float*)d_in[2];
    const float* bias  = (const float*)d_in[3];
    float* out = (float*)d_out;

    const size_t yE   = (size_t)N_B * 64 * NV;
    const size_t zE   = (size_t)N_B * 64 * NE;
    const size_t HBW  = (size_t)N_B * (NV / 16) * (NE / 32) * 16;
    const size_t HTW  = (size_t)N_B * (NE / 16) * (NV / 32) * 16;
    const size_t depE = (size_t)64 * N_B * NE;
    const size_t dvpE = (size_t)32 * N_B * NV;
    const size_t deE  = (size_t)N_B * NE;
    const size_t dvE  = (size_t)N_B * NV;

    u16* Yh = (u16*)d_ws;
    u16* Yl = Yh + yE;
    u16* Zh = Yl + yE;
    u16* Zl = Zh + zE;
    uint32_t* HB = (uint32_t*)(Zl + zE);
    uint32_t* HT = HB + HBW;
    float* deP = (float*)(HT + HTW);
    float* dvP = deP + depE;
    float* de  = dvP + dvpE;
    float* dv  = de + deE;
    float* fbase = dv + dvE;

    const size_t fixed_bytes = (size_t)((char*)fbase - (char*)d_ws);
    const size_t avail_f = (ws_size > fixed_bytes) ? (ws_size - fixed_bytes) / 4 : 0;

    const size_t unit2 = zE;
    const size_t unit3 = yE;
    // s2/s3 tiers chosen so S = (K/splits)/32 is a multiple of 4 and >= 8
    int s2 = 1, s3 = 1;
    if      (avail_f >= 8 * unit2 + 4 * unit3) { s2 = 8; s3 = 4; }
    else if (avail_f >= 4 * unit2 + 2 * unit3) { s2 = 4; s3 = 2; }
    else if (avail_f >= 2 * unit2 + 1 * unit3) { s2 = 2; s3 = 1; }

    float* P2 = fbase;
    float* P3 = P2 + (size_t)s2 * zE;

    k_pack<<<dim3(NE / 64, NV / 64, N_B), 256, 0, stream>>>(H, HB, HT, dvP, deP);
    k_xtheta<<<dim3(N_B * NV / 64), 256, 0, stream>>>(x, theta, Yh, Yl);
    k_deg<<<dim3((N_B * NE + N_B * NV) / 256), 256, 0, stream>>>(dvP, deP, dv, de);
    k_v2e<<<dim3(NE / 64, s2, N_B), 256, 0, stream>>>(HT, Yh, Yl, P2);
    k_red2<<<dim3((int)(zE / 4 / 256)), 256, 0, stream>>>(P2, de, Zh, Zl, s2);
    k_e2v<<<dim3(NV / 64, s3, N_B), 256, 0, stream>>>(HB, Zh, Zl, P3);
    k_red3<<<dim3(NV / 64, N_B), 512, 0, stream>>>(P3, dv, bias, out, s3);
}